// Round 4
// baseline (271.277 us; speedup 1.0000x reference)
//
#include <hip/hip_runtime.h>

typedef unsigned short u16;
typedef __attribute__((ext_vector_type(8))) short bf16x8;
typedef __attribute__((ext_vector_type(2))) float f32x2;
typedef __attribute__((ext_vector_type(4))) float f32x4;

#define NPTS 65536
#define MTOT 1048576            // NPTS * NS
#define M2TOT 131072            // sampled pairs for BN2/BN3 stats (NPTS/8 * 16)
#define EPSb 1e-5f

// ---- workspace layout ----
// float-offsets from ws base:
#define XQ_OFF  0u              // f32 [NPTS,64]            16 MB
#define T_OFF   4194304u        // f32 [MTOT,3]; raw after k1, bn1+relu'd after k1b
#define ST_OFF  15728640u       // f32 [150] stats
// ushort-offsets from ws base:
#define XK_US   31457792u       // bf16 [NPTS,64]            8 MB
#define XV_US   35652096u       // bf16 [NPTS,64]            8 MB

__device__ __forceinline__ float bf2f(u16 h) {
    return __uint_as_float(((unsigned)h) << 16);
}
__device__ __forceinline__ u16 f2bf(float f) {          // RNE
    unsigned u = __float_as_uint(f);
    u += 0x7fffu + ((u >> 16) & 1u);
    return (u16)(u >> 16);
}
__device__ __forceinline__ unsigned cvt_pk_bf16(float lo, float hi) {
    unsigned r;
    asm("v_cvt_pk_bf16_f32 %0, %1, %2" : "=v"(r) : "v"(lo), "v"(hi));
    return r;
}
__device__ __forceinline__ bf16x8 pack_bf8(const float4 lo, const float4 hi) {
    union { bf16x8 v; unsigned u[4]; } r;
    r.u[0] = cvt_pk_bf16(lo.x, lo.y);
    r.u[1] = cvt_pk_bf16(lo.z, lo.w);
    r.u[2] = cvt_pk_bf16(hi.x, hi.y);
    r.u[3] = cvt_pk_bf16(hi.z, hi.w);
    return r.v;
}

// bn2-folded constants for one 8-channel chunk, stored as f32x2 pairs so the
// fragment build can use packed (v_pk_fma_f32) math.
struct BN2C {
    f32x2 A2[4], D[4], W0[4], W1[4], W2[4];
};
__device__ __forceinline__ void bn2c_build(
    BN2C& c, const int kbase, const float* __restrict__ ws,
    const float* __restrict__ gw1, const float* __restrict__ bw1_bn,
    const float* __restrict__ bp2, const float* __restrict__ Wp2)
{
    const float invM2 = 1.0f / (float)M2TOT;
#pragma unroll
    for (int j = 0; j < 4; ++j) {
        float a2[2], d[2], w0[2], w1[2], w2[2];
#pragma unroll
        for (int h = 0; h < 2; ++h) {
            const int k = kbase + 2 * j + h;
            const float mean = ws[ST_OFF + 6 + k] * invM2;
            const float var  = ws[ST_OFF + 70 + k] * invM2 - mean * mean;
            const float A2 = gw1[k] * rsqrtf(var + EPSb);
            const float B2 = bw1_bn[k] - mean * A2;
            a2[h] = A2; d[h] = fmaf(A2, bp2[k], B2);
            w0[h] = A2 * Wp2[k]; w1[h] = A2 * Wp2[64 + k]; w2[h] = A2 * Wp2[128 + k];
        }
        c.A2[j] = f32x2{a2[0], a2[1]}; c.D[j] = f32x2{d[0], d[1]};
        c.W0[j] = f32x2{w0[0], w0[1]}; c.W1[j] = f32x2{w1[0], w1[1]};
        c.W2[j] = f32x2{w2[0], w2[1]};
    }
}
// A-fragment: a[i] = bf16(relu(A2*(xk - xq + pr) + B2)), packed-math form.
__device__ __forceinline__ bf16x8 build_frag(
    const BN2C& c, const f32x2 t0v, const f32x2 t1v, const f32x2 t2v,
    const uint4 g, const float4 xlo, const float4 xhi)
{
    union { bf16x8 v; unsigned u[4]; } r;
    const unsigned gu[4] = { g.x, g.y, g.z, g.w };
    const f32x2 xp[4] = { {xlo.x, xlo.y}, {xlo.z, xlo.w}, {xhi.x, xhi.y}, {xhi.z, xhi.w} };
#pragma unroll
    for (int j = 0; j < 4; ++j) {
        f32x2 gf;
        gf.x = __uint_as_float(gu[j] << 16);
        gf.y = __uint_as_float(gu[j] & 0xffff0000u);
        f32x2 v = c.D[j] - c.A2[j] * xp[j];
        v = v + t0v * c.W0[j];
        v = v + t1v * c.W1[j];
        v = v + t2v * c.W2[j];
        v = v + c.A2[j] * gf;
        r.u[j] = cvt_pk_bf16(fmaxf(v.x, 0.0f), fmaxf(v.y, 0.0f));
    }
    return r.v;
}

// Ww1 B-fragments for the 64x8 MFMA (cols 8..15 zero), built from f32 weights.
__device__ __forceinline__ void load_b_frags(
    const float* __restrict__ Ww1, const int col16, const int quad,
    bf16x8& b0, bf16x8& b1)
{
    b0 = bf16x8{0,0,0,0,0,0,0,0};
    b1 = bf16x8{0,0,0,0,0,0,0,0};
    if (col16 < 8) {
#pragma unroll
        for (int j = 0; j < 8; ++j) {
            const int k0 = quad * 8 + j;
            b0[j] = (short)f2bf(Ww1[k0 * 8 + col16]);
            b1[j] = (short)f2bf(Ww1[(k0 + 32) * 8 + col16]);
        }
    }
}

// ---------------------------------------------------------------------------
// K1: xq/xk/xv projections via MFMA ([65536,64] @ [64,192] bf16) + BN1 stats.
// grid=512 x 256: wave = 2 groups of 16 points. bf16 weight table built
// cooperatively in LDS (no separate prep dispatch).
// ---------------------------------------------------------------------------
__global__ __launch_bounds__(256) void k1_proj_bn1(
    const float* __restrict__ p, const float* __restrict__ x, const int* __restrict__ idx,
    const float* __restrict__ Wq, const float* __restrict__ Wk, const float* __restrict__ Wv,
    const float* __restrict__ bq, const float* __restrict__ bk, const float* __restrict__ bv,
    const float* __restrict__ Wp1, const float* __restrict__ bp1,
    float* __restrict__ ws)
{
    u16* wsu = (u16*)ws;
    __shared__ u16 wtab[12288];          // WT[m][n][c] = bf16(Wm[c][n]), 24 KB
    __shared__ float sred[6];
    const int tid   = threadIdx.x;
    const int lane  = tid & 63;
    const int wid   = tid >> 6;
    const int col16 = lane & 15;
    const int quad  = lane >> 4;
    if (tid < 6) sred[tid] = 0.0f;

    // build bf16 weight table in LDS (48 entries per thread)
#pragma unroll
    for (int k = 0; k < 48; ++k) {
        const int e = tid + k * 256;            // 0..12287
        const float* W = (e < 4096) ? Wq : ((e < 8192) ? Wk : Wv);
        const int rem = e & 4095;
        const int n = rem >> 6, c = rem & 63;
        wtab[e] = f2bf(W[c * 64 + n]);
    }
    __syncthreads();

    bf16x8 bf[3][4][2];
#pragma unroll
    for (int M = 0; M < 3; ++M)
#pragma unroll
        for (int t = 0; t < 4; ++t)
#pragma unroll
            for (int h = 0; h < 2; ++h)
                bf[M][t][h] = *(const bf16x8*)&wtab[
                    (unsigned)(M * 4096 + (t * 16 + col16) * 64 + h * 32 + quad * 8)];

    float bq_t[4], bk_t[4], bv_t[4];
#pragma unroll
    for (int t = 0; t < 4; ++t) {
        bq_t[t] = bq[t * 16 + col16];
        bk_t[t] = bk[t * 16 + col16];
        bv_t[t] = bv[t * 16 + col16];
    }

    float* xq   = ws + XQ_OFF;
    u16*  xkb   = wsu + XK_US;
    u16*  xvb   = wsu + XV_US;

    const int gw = blockIdx.x * 4 + wid;              // 0..2047
#pragma unroll
    for (int g = 0; g < 2; ++g) {
        const int n0 = (gw * 2 + g) * 16;
        const float* xrow = x + (unsigned)(n0 + col16) * 64u;
        const float4 fa0 = *(const float4*)&xrow[quad * 8];
        const float4 fa1 = *(const float4*)&xrow[quad * 8 + 4];
        const float4 fb0 = *(const float4*)&xrow[32 + quad * 8];
        const float4 fb1 = *(const float4*)&xrow[32 + quad * 8 + 4];
        const bf16x8 a0 = pack_bf8(fa0, fa1);
        const bf16x8 a1 = pack_bf8(fb0, fb1);

#pragma unroll
        for (int t = 0; t < 4; ++t) {
            f32x4 aq = {0,0,0,0}, ak = {0,0,0,0}, av = {0,0,0,0};
            aq = __builtin_amdgcn_mfma_f32_16x16x32_bf16(a0, bf[0][t][0], aq, 0, 0, 0);
            aq = __builtin_amdgcn_mfma_f32_16x16x32_bf16(a1, bf[0][t][1], aq, 0, 0, 0);
            ak = __builtin_amdgcn_mfma_f32_16x16x32_bf16(a0, bf[1][t][0], ak, 0, 0, 0);
            ak = __builtin_amdgcn_mfma_f32_16x16x32_bf16(a1, bf[1][t][1], ak, 0, 0, 0);
            av = __builtin_amdgcn_mfma_f32_16x16x32_bf16(a0, bf[2][t][0], av, 0, 0, 0);
            av = __builtin_amdgcn_mfma_f32_16x16x32_bf16(a1, bf[2][t][1], av, 0, 0, 0);
#pragma unroll
            for (int r = 0; r < 4; ++r) {
                const unsigned row = (unsigned)(n0 + quad * 4 + r);
                const unsigned o   = row * 64u + (unsigned)(t * 16 + col16);
                xq[o]  = aq[r] + bq_t[t];
                xkb[o] = f2bf(ak[r] + bk_t[t]);
                xvb[o] = f2bf(av[r] + bv_t[t]);
            }
        }
    }

    // ---- BN1 stats + store raw T: this block's 2048 pairs ----
    const int base = blockIdx.x * 128;
    const float w00 = Wp1[0], w01 = Wp1[1], w02 = Wp1[2];
    const float w10 = Wp1[3], w11 = Wp1[4], w12 = Wp1[5];
    const float w20 = Wp1[6], w21 = Wp1[7], w22 = Wp1[8];
    const float c0 = bp1[0], c1 = bp1[1], c2 = bp1[2];
    float s0 = 0, s1 = 0, s2 = 0, q0 = 0, q1 = 0, q2 = 0;
#pragma unroll
    for (int m = 0; m < 8; ++m) {
        const int pl = tid + m * 256;            // 0..2047
        const int n  = base + (pl >> 4);
        const unsigned gpair = (unsigned)(base * 16 + pl);
        const int nb = idx[gpair];
        const float r0 = p[nb * 3 + 0] - p[n * 3 + 0];
        const float r1 = p[nb * 3 + 1] - p[n * 3 + 1];
        const float r2 = p[nb * 3 + 2] - p[n * 3 + 2];
        const float t0 = c0 + r0 * w00 + r1 * w10 + r2 * w20;
        const float t1 = c1 + r0 * w01 + r1 * w11 + r2 * w21;
        const float t2 = c2 + r0 * w02 + r1 * w12 + r2 * w22;
        ws[T_OFF + gpair * 3u + 0u] = t0;
        ws[T_OFF + gpair * 3u + 1u] = t1;
        ws[T_OFF + gpair * 3u + 2u] = t2;
        s0 += t0; s1 += t1; s2 += t2;
        q0 += t0 * t0; q1 += t1 * t1; q2 += t2 * t2;
    }
    atomicAdd(&sred[0], s0); atomicAdd(&sred[1], s1); atomicAdd(&sred[2], s2);
    atomicAdd(&sred[3], q0); atomicAdd(&sred[4], q1); atomicAdd(&sred[5], q2);
    __syncthreads();
    if (tid < 6) atomicAdd(&ws[ST_OFF + tid], sred[tid]);
}

// ---------------------------------------------------------------------------
// K1b: apply BN1+ReLU to T in place (T -> T'). grid=1024 x 256.
// ---------------------------------------------------------------------------
__global__ __launch_bounds__(256) void k1b_bn1apply(
    const float* __restrict__ gp, const float* __restrict__ bp_bn,
    float* __restrict__ ws)
{
    const float invM = 1.0f / (float)MTOT;
    float A1[3], B1[3];
#pragma unroll
    for (int a = 0; a < 3; ++a) {
        const float mean = ws[ST_OFF + a] * invM;
        const float var  = ws[ST_OFF + 3 + a] * invM - mean * mean;
        const float sc = gp[a] * rsqrtf(var + EPSb);
        A1[a] = sc; B1[a] = bp_bn[a] - mean * sc;
    }
    const unsigned t = blockIdx.x * 256u + threadIdx.x;   // 0..262143
    float4* Tp = (float4*)(ws + T_OFF + t * 12u);
    float4 v0 = Tp[0], v1 = Tp[1], v2 = Tp[2];
    v0.x = fmaxf(fmaf(v0.x, A1[0], B1[0]), 0.0f);
    v0.y = fmaxf(fmaf(v0.y, A1[1], B1[1]), 0.0f);
    v0.z = fmaxf(fmaf(v0.z, A1[2], B1[2]), 0.0f);
    v0.w = fmaxf(fmaf(v0.w, A1[0], B1[0]), 0.0f);
    v1.x = fmaxf(fmaf(v1.x, A1[1], B1[1]), 0.0f);
    v1.y = fmaxf(fmaf(v1.y, A1[2], B1[2]), 0.0f);
    v1.z = fmaxf(fmaf(v1.z, A1[0], B1[0]), 0.0f);
    v1.w = fmaxf(fmaf(v1.w, A1[1], B1[1]), 0.0f);
    v2.x = fmaxf(fmaf(v2.x, A1[2], B1[2]), 0.0f);
    v2.y = fmaxf(fmaf(v2.y, A1[0], B1[0]), 0.0f);
    v2.z = fmaxf(fmaf(v2.z, A1[1], B1[1]), 0.0f);
    v2.w = fmaxf(fmaf(v2.w, A1[2], B1[2]), 0.0f);
    Tp[0] = v0; Tp[1] = v1; Tp[2] = v2;
}

// ---------------------------------------------------------------------------
// K2': SAMPLED BN2 stats over w0 = xk[idx] - xq + pr (every 8th point).
// grid=512 x 256, wave = 4 sampled points. NO stores.
// ---------------------------------------------------------------------------
__global__ __launch_bounds__(256) void k2_bn2(
    const int* __restrict__ idx,
    const float* __restrict__ Wp2, const float* __restrict__ bp2,
    float* __restrict__ ws)
{
    u16* wsu = (u16*)ws;
    __shared__ float ss[64], sq[64];
    const int tid = threadIdx.x;
    const int lane = tid & 63;
    const int gw = blockIdx.x * 4 + (tid >> 6);       // 0..2047
    if (tid < 64) { ss[tid] = 0.0f; sq[tid] = 0.0f; }

    const float wp20 = Wp2[lane], wp21 = Wp2[64 + lane], wp22 = Wp2[128 + lane];
    const float bp2c = bp2[lane];
    const float* xq  = ws + XQ_OFF;
    const float* T   = ws + T_OFF;
    const u16*  xkb  = wsu + XK_US;

    float s = 0.0f, q = 0.0f;

    for (int nn = 0; nn < 4; ++nn) {
        const int nu = __builtin_amdgcn_readfirstlane((gw * 4 + nn) * 8);

        const int4* ir4 = (const int4*)(idx + (unsigned)nu * 16u);
        const int4 i0 = ir4[0], i1 = ir4[1], i2 = ir4[2], i3 = ir4[3];
        const int nbs[16] = { i0.x, i0.y, i0.z, i0.w, i1.x, i1.y, i1.z, i1.w,
                              i2.x, i2.y, i2.z, i2.w, i3.x, i3.y, i3.z, i3.w };
        u16 kr[16];
#pragma unroll
        for (int j = 0; j < 16; ++j) kr[j] = xkb[(unsigned)nbs[j] * 64u + lane];

        float tr[48];
        const float4* Tr4 = (const float4*)(T + (unsigned)nu * 48u);
#pragma unroll
        for (int c = 0; c < 12; ++c) {
            const float4 v = Tr4[c];
            tr[4 * c + 0] = v.x; tr[4 * c + 1] = v.y;
            tr[4 * c + 2] = v.z; tr[4 * c + 3] = v.w;
        }
        const float xqc  = xq[(unsigned)nu * 64u + lane];
        const float base = bp2c - xqc;

#pragma unroll
        for (int j = 0; j < 16; ++j) {
            const float prx = base + tr[3 * j + 0] * wp20
                                   + tr[3 * j + 1] * wp21
                                   + tr[3 * j + 2] * wp22;
            const float w0 = bf2f(kr[j]) + prx;
            s += w0; q = fmaf(w0, w0, q);
        }
    }
    __syncthreads();
    atomicAdd(&ss[lane], s); atomicAdd(&sq[lane], q);
    __syncthreads();
    if (tid < 64) {
        atomicAdd(&ws[ST_OFF + 6 + tid], ss[tid]);
        atomicAdd(&ws[ST_OFF + 70 + tid], sq[tid]);
    }
}

// ---------------------------------------------------------------------------
// K2b: SAMPLED BN3 stats — w1 = relu(bn2(w0)) @ Ww1 + bw1 for every 8th
// point (same MFMA path as k34), accumulate sums only. grid=256 x 256.
// ---------------------------------------------------------------------------
__global__ __launch_bounds__(256) void k2b_bn3(
    const int* __restrict__ idx,
    const float* __restrict__ Wp2, const float* __restrict__ bp2,
    const float* __restrict__ gw1, const float* __restrict__ bw1_bn,
    const float* __restrict__ Ww1, const float* __restrict__ bw1,
    float* __restrict__ ws)
{
    u16* wsu = (u16*)ws;
    __shared__ float s3r[8], q3r[8];
    const int tid   = threadIdx.x;
    const int lane  = tid & 63;
    const int wid   = tid >> 6;
    const int col16 = lane & 15;
    const int quad  = lane >> 4;
    if (tid < 8) { s3r[tid] = 0.0f; q3r[tid] = 0.0f; }
    __syncthreads();

    BN2C cA, cB;
    bn2c_build(cA, quad * 8,      ws, gw1, bw1_bn, bp2, Wp2);
    bn2c_build(cB, 32 + quad * 8, ws, gw1, bw1_bn, bp2, Wp2);

    bf16x8 b0, b1;
    load_b_frags(Ww1, col16, quad, b0, b1);
    const float bw1c = (col16 < 8) ? bw1[col16] : 0.0f;

    const float* xq  = ws + XQ_OFF;
    const float* T   = ws + T_OFF;
    const u16*  xkb  = wsu + XK_US;
    const int sg = (blockIdx.x * 4 + wid) * 8;        // sampled-point group base
    float bs = 0.0f, bq2 = 0.0f;

    for (int it = 0; it < 8; ++it) {
        const int nu = __builtin_amdgcn_readfirstlane((sg + it) * 8);

        const int nbv = idx[(unsigned)nu * 16u + (unsigned)col16];
        const u16* grow = xkb + (unsigned)nbv * 64u;
        const uint4 gA = *(const uint4*)(grow + quad * 8);
        const uint4 gB = *(const uint4*)(grow + 32 + quad * 8);

        const float* Trow = T + (unsigned)nu * 48u + (unsigned)col16 * 3u;
        const f32x2 t0v = f32x2{Trow[0], Trow[0]};
        const f32x2 t1v = f32x2{Trow[1], Trow[1]};
        const f32x2 t2v = f32x2{Trow[2], Trow[2]};

        const float* xr = xq + (unsigned)nu * 64u;
        const float4 x0 = *(const float4*)(xr + quad * 8);
        const float4 x1 = *(const float4*)(xr + quad * 8 + 4);
        const float4 x2 = *(const float4*)(xr + 32 + quad * 8);
        const float4 x3 = *(const float4*)(xr + 32 + quad * 8 + 4);

        const bf16x8 a0 = build_frag(cA, t0v, t1v, t2v, gA, x0, x1);
        const bf16x8 a1 = build_frag(cB, t0v, t1v, t2v, gB, x2, x3);

        f32x4 acc = {0.0f, 0.0f, 0.0f, 0.0f};
        acc = __builtin_amdgcn_mfma_f32_16x16x32_bf16(a0, b0, acc, 0, 0, 0);
        acc = __builtin_amdgcn_mfma_f32_16x16x32_bf16(a1, b1, acc, 0, 0, 0);
        if (col16 < 8) {
#pragma unroll
            for (int r = 0; r < 4; ++r) {
                const float o = acc[r] + bw1c;
                bs += o;
                bq2 = fmaf(o, o, bq2);
            }
        }
    }
    if (col16 < 8) {
        atomicAdd(&s3r[col16], bs);
        atomicAdd(&q3r[col16], bq2);
    }
    __syncthreads();
    if (tid < 8) {
        atomicAdd(&ws[ST_OFF + 134 + tid], s3r[tid]);
        atomicAdd(&ws[ST_OFF + 142 + tid], q3r[tid]);
    }
}

// ---------------------------------------------------------------------------
// K34: fused K3+K4. grid=2048 x 256, wave = 8 points, no barriers.
// ---------------------------------------------------------------------------
__global__ __launch_bounds__(256) void k34_fused(
    const int* __restrict__ idx,
    const float* __restrict__ Wp2, const float* __restrict__ bp2,
    const float* __restrict__ gw1, const float* __restrict__ bw1_bn,
    const float* __restrict__ Ww1, const float* __restrict__ bw1,
    const float* __restrict__ gw2, const float* __restrict__ bw2_bn,
    const float* __restrict__ Ww2, const float* __restrict__ bw2,
    const float* __restrict__ ws, float* __restrict__ out)
{
    const u16* wsu = (const u16*)ws;
    __shared__ float sv3[4][16][8];
    __shared__ float se[4][16][8];
    const int tid   = threadIdx.x;
    const int lane  = tid & 63;
    const int wid   = tid >> 6;
    const int col16 = lane & 15;
    const int quad  = lane >> 4;
    const int tt    = lane & 7;
    const int j1    = lane >> 3;

    const float invM2 = 1.0f / (float)M2TOT;
    BN2C cA, cB;
    bn2c_build(cA, quad * 8,      ws, gw1, bw1_bn, bp2, Wp2);
    bn2c_build(cB, 32 + quad * 8, ws, gw1, bw1_bn, bp2, Wp2);

    bf16x8 b0, b1;
    load_b_frags(Ww1, col16, quad, b0, b1);
    const float bw1c = (col16 < 8) ? bw1[col16] : 0.0f;
    // bn3 (sampled stats) by output channel col16&7, bw1 bias folded in
    const int   c3    = col16 & 7;
    const float mean3 = ws[ST_OFF + 134 + c3] * invM2;
    const float var3  = ws[ST_OFF + 142 + c3] * invM2 - mean3 * mean3;
    const float A3c   = gw2[c3] * rsqrtf(var3 + EPSb);
    const float B3f   = fmaf(A3c, bw1c, bw2_bn[c3] - mean3 * A3c);
    // Ww2 by tt (softmax-logit matmul) + aggregation constants
    float ww2c[8];
#pragma unroll
    for (int u = 0; u < 8; ++u) ww2c[u] = Ww2[u * 8 + tt];
    const float bw2c = bw2[tt];
    const float wp20 = Wp2[lane], wp21 = Wp2[64 + lane], wp22 = Wp2[128 + lane];
    const float bp2c = bp2[lane];

    const float* xq  = ws + XQ_OFF;
    const float* T   = ws + T_OFF;
    const u16*  xkb  = wsu + XK_US;
    const u16*  xvb  = wsu + XV_US;

    const int n0 = (blockIdx.x * 4 + wid) * 8;
    for (int it = 0; it < 8; ++it) {
        const int nu = __builtin_amdgcn_readfirstlane(n0 + it);

        // scalar idx row (for xv gather)
        const int4* ir4 = (const int4*)(idx + (unsigned)nu * 16u);
        const int4 i0 = ir4[0], i1 = ir4[1], i2 = ir4[2], i3 = ir4[3];
        const int nbs[16] = { i0.x, i0.y, i0.z, i0.w, i1.x, i1.y, i1.z, i1.w,
                              i2.x, i2.y, i2.z, i2.w, i3.x, i3.y, i3.z, i3.w };
        // per-lane pair row (MFMA A gather)
        const int nbv = idx[(unsigned)nu * 16u + (unsigned)col16];
        const u16* grow = xkb + (unsigned)nbv * 64u;
        const uint4 gA = *(const uint4*)(grow + quad * 8);
        const uint4 gB = *(const uint4*)(grow + 32 + quad * 8);
        // xv gather (lane = channel) — issue early to overlap MFMA chain
        u16 xvr[16];
#pragma unroll
        for (int j = 0; j < 16; ++j) xvr[j] = xvb[(unsigned)nbs[j] * 64u + lane];

        // per-lane t' (MFMA path) — T already bn1+relu'd
        const float* Trow = T + (unsigned)nu * 48u + (unsigned)col16 * 3u;
        const f32x2 t0v = f32x2{Trow[0], Trow[0]};
        const f32x2 t1v = f32x2{Trow[1], Trow[1]};
        const f32x2 t2v = f32x2{Trow[2], Trow[2]};
        // scalar t' row (aggregation path)
        float tr[48];
        const float4* Tr4 = (const float4*)(T + (unsigned)nu * 48u);
#pragma unroll
        for (int c = 0; c < 12; ++c) {
            const float4 v = Tr4[c];
            tr[4 * c + 0] = v.x; tr[4 * c + 1] = v.y;
            tr[4 * c + 2] = v.z; tr[4 * c + 3] = v.w;
        }
        // xq row (wave-uniform, quad-dependent chunks)
        const float* xr = xq + (unsigned)nu * 64u;
        const float4 x0 = *(const float4*)(xr + quad * 8);
        const float4 x1 = *(const float4*)(xr + quad * 8 + 4);
        const float4 x2 = *(const float4*)(xr + 32 + quad * 8);
        const float4 x3 = *(const float4*)(xr + 32 + quad * 8 + 4);

        // build A fragments (packed math + cvt_pk)
        const bf16x8 a0 = build_frag(cA, t0v, t1v, t2v, gA, x0, x1);
        const bf16x8 a1 = build_frag(cB, t0v, t1v, t2v, gB, x2, x3);

        f32x4 acc = {0.0f, 0.0f, 0.0f, 0.0f};
        acc = __builtin_amdgcn_mfma_f32_16x16x32_bf16(a0, b0, acc, 0, 0, 0);
        acc = __builtin_amdgcn_mfma_f32_16x16x32_bf16(a1, b1, acc, 0, 0, 0);

        // bn3 + relu epilogue -> wave-private LDS (C layout: row=quad*4+r)
        if (col16 < 8) {
#pragma unroll
            for (int r = 0; r < 4; ++r)
                sv3[wid][quad * 4 + r][col16] = fmaxf(fmaf(A3c, acc[r], B3f), 0.0f);
        }
        // 8x8 matmul: logits for neighbors j1 and j1+8 at plane tt
        float s0 = bw2c, s1 = bw2c;
#pragma unroll
        for (int u = 0; u < 8; ++u) {
            s0 = fmaf(sv3[wid][j1][u], ww2c[u], s0);
            s1 = fmaf(sv3[wid][j1 + 8][u], ww2c[u], s1);
        }
        // softmax over 16 neighbors: butterfly across the 8 lanes sharing tt
        float mx = fmaxf(s0, s1);
        mx = fmaxf(mx, __shfl_xor(mx, 8));
        mx = fmaxf(mx, __shfl_xor(mx, 16));
        mx = fmaxf(mx, __shfl_xor(mx, 32));
        const float e0 = __expf(s0 - mx);
        const float e1 = __expf(s1 - mx);
        float sm = e0 + e1;
        sm += __shfl_xor(sm, 8);
        sm += __shfl_xor(sm, 16);
        sm += __shfl_xor(sm, 32);
        const float rs = __builtin_amdgcn_rcpf(sm);
        se[wid][j1][tt]     = e0 * rs;
        se[wid][j1 + 8][tt] = e1 * rs;

        // factored aggregation: out = sum(e*xv) + (sum(e*t')).Wp2col + bp2c
        float xvacc = 0.0f, ta0 = 0.0f, ta1 = 0.0f, ta2 = 0.0f;
#pragma unroll
        for (int j = 0; j < 16; ++j) {
            const float ej = se[wid][j][tt];
            xvacc = fmaf(bf2f(xvr[j]), ej, xvacc);
            ta0 = fmaf(tr[3 * j + 0], ej, ta0);
            ta1 = fmaf(tr[3 * j + 1], ej, ta1);
            ta2 = fmaf(tr[3 * j + 2], ej, ta2);
        }
        out[(unsigned)nu * 64u + lane] =
            fmaf(ta0, wp20, fmaf(ta1, wp21, fmaf(ta2, wp22, xvacc + bp2c)));
    }
}

extern "C" void kernel_launch(void* const* d_in, const int* in_sizes, int n_in,
                              void* d_out, int out_size, void* d_ws, size_t ws_size,
                              hipStream_t stream)
{
    const float* p      = (const float*)d_in[0];
    const float* x      = (const float*)d_in[1];
    const int*   idx    = (const int*)d_in[2];
    const float* Wq     = (const float*)d_in[3];
    const float* bq     = (const float*)d_in[4];
    const float* Wk     = (const float*)d_in[5];
    const float* bk     = (const float*)d_in[6];
    const float* Wv     = (const float*)d_in[7];
    const float* bv     = (const float*)d_in[8];
    const float* Wp1    = (const float*)d_in[9];
    const float* bp1    = (const float*)d_in[10];
    const float* gp     = (const float*)d_in[11];
    const float* bp_bn  = (const float*)d_in[12];
    const float* Wp2    = (const float*)d_in[13];
    const float* bp2    = (const float*)d_in[14];
    const float* gw1    = (const float*)d_in[15];
    const float* bw1_bn = (const float*)d_in[16];
    const float* Ww1    = (const float*)d_in[17];
    const float* bw1    = (const float*)d_in[18];
    const float* gw2    = (const float*)d_in[19];
    const float* bw2_bn = (const float*)d_in[20];
    const float* Ww2    = (const float*)d_in[21];
    const float* bw2    = (const float*)d_in[22];
    float* ws  = (float*)d_ws;
    float* out = (float*)d_out;
    (void)in_sizes; (void)n_in; (void)out_size; (void)ws_size;

    hipMemsetAsync((char*)d_ws + (size_t)ST_OFF * 4, 0, 150 * sizeof(float), stream);

    k1_proj_bn1<<<512, 256, 0, stream>>>(p, x, idx, Wq, Wk, Wv,
                                         bq, bk, bv, Wp1, bp1, ws);
    k1b_bn1apply<<<1024, 256, 0, stream>>>(gp, bp_bn, ws);
    k2_bn2<<<512, 256, 0, stream>>>(idx, Wp2, bp2, ws);
    k2b_bn3<<<256, 256, 0, stream>>>(idx, Wp2, bp2, gw1, bw1_bn, Ww1, bw1, ws);
    k34_fused<<<2048, 256, 0, stream>>>(idx, Wp2, bp2, gw1, bw1_bn, Ww1, bw1,
                                        gw2, bw2_bn, Ww2, bw2, ws, out);
}

// Round 5
// 252.071 us; speedup vs baseline: 1.0762x; 1.0762x over previous
//
#include <hip/hip_runtime.h>

typedef unsigned short u16;
typedef __attribute__((ext_vector_type(8))) short bf16x8;
typedef __attribute__((ext_vector_type(2))) float f32x2;
typedef __attribute__((ext_vector_type(4))) float f32x4;

#define NPTS 65536
#define MTOT 1048576            // NPTS * NS
#define M2TOT 131072            // sampled pairs for BN2/BN3 stats (NPTS/8 * 16)
#define EPSb 1e-5f

// ---- workspace layout ----
// float-offsets from ws base:
#define XQ_OFF  0u              // f32 [NPTS,64]            16 MB
#define T_OFF   4194304u        // f32 [MTOT,3] T' (bn1+relu applied at creation)
#define ST_OFF  15728640u       // f32 [150] stats
// ushort-offsets from ws base:
#define XK_US   31457792u       // bf16 [NPTS,64]            8 MB
#define XV_US   35652096u       // bf16 [NPTS,64]            8 MB
// bf16 weight tables (gap between T and ST):
#define WTQ_US  14680064u       // bf16 WT[3][64][64]: WT[m][n][c] = bf16(Wm[c][n])
#define WT1_US  14692352u       // bf16 WT1[8][64]:    WT1[c][r]   = bf16(Ww1[r][c])

__device__ __forceinline__ float bf2f(u16 h) {
    return __uint_as_float(((unsigned)h) << 16);
}
__device__ __forceinline__ u16 f2bf(float f) {          // RNE
    unsigned u = __float_as_uint(f);
    u += 0x7fffu + ((u >> 16) & 1u);
    return (u16)(u >> 16);
}
__device__ __forceinline__ unsigned cvt_pk_bf16(float lo, float hi) {
    unsigned r;
    asm("v_cvt_pk_bf16_f32 %0, %1, %2" : "=v"(r) : "v"(lo), "v"(hi));
    return r;
}
__device__ __forceinline__ bf16x8 pack_bf8(const float4 lo, const float4 hi) {
    union { bf16x8 v; unsigned u[4]; } r;
    r.u[0] = cvt_pk_bf16(lo.x, lo.y);
    r.u[1] = cvt_pk_bf16(lo.z, lo.w);
    r.u[2] = cvt_pk_bf16(hi.x, hi.y);
    r.u[3] = cvt_pk_bf16(hi.z, hi.w);
    return r.v;
}

// bn2-folded constants for one 8-channel chunk, stored as f32x2 pairs so the
// fragment build can use packed (v_pk_fma_f32) math.
struct BN2C {
    f32x2 A2[4], D[4], W0[4], W1[4], W2[4];
};
__device__ __forceinline__ void bn2c_build(
    BN2C& c, const int kbase, const float* __restrict__ ws,
    const float* __restrict__ gw1, const float* __restrict__ bw1_bn,
    const float* __restrict__ bp2, const float* __restrict__ Wp2)
{
    const float invM2 = 1.0f / (float)M2TOT;
#pragma unroll
    for (int j = 0; j < 4; ++j) {
        float a2[2], d[2], w0[2], w1[2], w2[2];
#pragma unroll
        for (int h = 0; h < 2; ++h) {
            const int k = kbase + 2 * j + h;
            const float mean = ws[ST_OFF + 6 + k] * invM2;
            const float var  = ws[ST_OFF + 70 + k] * invM2 - mean * mean;
            const float A2 = gw1[k] * rsqrtf(var + EPSb);
            const float B2 = bw1_bn[k] - mean * A2;
            a2[h] = A2; d[h] = fmaf(A2, bp2[k], B2);
            w0[h] = A2 * Wp2[k]; w1[h] = A2 * Wp2[64 + k]; w2[h] = A2 * Wp2[128 + k];
        }
        c.A2[j] = f32x2{a2[0], a2[1]}; c.D[j] = f32x2{d[0], d[1]};
        c.W0[j] = f32x2{w0[0], w0[1]}; c.W1[j] = f32x2{w1[0], w1[1]};
        c.W2[j] = f32x2{w2[0], w2[1]};
    }
}
// A-fragment: a[i] = bf16(relu(A2*(xk - xq + pr) + B2)), packed-math form.
__device__ __forceinline__ bf16x8 build_frag(
    const BN2C& c, const f32x2 t0v, const f32x2 t1v, const f32x2 t2v,
    const uint4 g, const float4 xlo, const float4 xhi)
{
    union { bf16x8 v; unsigned u[4]; } r;
    const unsigned gu[4] = { g.x, g.y, g.z, g.w };
    const f32x2 xp[4] = { {xlo.x, xlo.y}, {xlo.z, xlo.w}, {xhi.x, xhi.y}, {xhi.z, xhi.w} };
#pragma unroll
    for (int j = 0; j < 4; ++j) {
        f32x2 gf;
        gf.x = __uint_as_float(gu[j] << 16);
        gf.y = __uint_as_float(gu[j] & 0xffff0000u);
        f32x2 v = c.D[j] - c.A2[j] * xp[j];
        v = v + t0v * c.W0[j];
        v = v + t1v * c.W1[j];
        v = v + t2v * c.W2[j];
        v = v + c.A2[j] * gf;
        r.u[j] = cvt_pk_bf16(fmaxf(v.x, 0.0f), fmaxf(v.y, 0.0f));
    }
    return r.v;
}

// ---------------------------------------------------------------------------
// K0m: BN1 stats (6 sums of t over ALL pairs, no T store) + bf16 weight
// tables into ws. grid=512 x 256, 8 pairs/thread.
// ---------------------------------------------------------------------------
__global__ __launch_bounds__(256) void k0_mom_tab(
    const float* __restrict__ p, const int* __restrict__ idx,
    const float* __restrict__ Wq, const float* __restrict__ Wk,
    const float* __restrict__ Wv, const float* __restrict__ Ww1,
    const float* __restrict__ Wp1, const float* __restrict__ bp1,
    float* __restrict__ ws)
{
    u16* wsu = (u16*)ws;
    __shared__ float sred[6];
    const int tid = threadIdx.x;
    const int gid = blockIdx.x * 256 + tid;            // 0..131071
    if (tid < 6) sred[tid] = 0.0f;
    __syncthreads();

    // ---- weight tables (one-time, spread across grid) ----
    if (gid < 12288) {
        const float* W = (gid < 4096) ? Wq : ((gid < 8192) ? Wk : Wv);
        const int rem = gid & 4095;
        const int n = rem >> 6, c = rem & 63;
        wsu[WTQ_US + (unsigned)gid] = f2bf(W[c * 64 + n]);
    } else if (gid < 12800) {
        const int rem = gid - 12288;
        const int c = rem >> 6, r = rem & 63;
        wsu[WT1_US + (unsigned)rem] = f2bf(Ww1[r * 8 + c]);
    }

    // ---- BN1 sums over this block's 2048 pairs (no store) ----
    const int base = blockIdx.x * 128;
    const float w00 = Wp1[0], w01 = Wp1[1], w02 = Wp1[2];
    const float w10 = Wp1[3], w11 = Wp1[4], w12 = Wp1[5];
    const float w20 = Wp1[6], w21 = Wp1[7], w22 = Wp1[8];
    const float c0 = bp1[0], c1 = bp1[1], c2 = bp1[2];
    float s0 = 0, s1 = 0, s2 = 0, q0 = 0, q1 = 0, q2 = 0;
#pragma unroll
    for (int m = 0; m < 8; ++m) {
        const int pl = tid + m * 256;                  // 0..2047
        const int n  = base + (pl >> 4);
        const unsigned gpair = (unsigned)(base * 16 + pl);
        const int nb = idx[gpair];
        const float r0 = p[nb * 3 + 0] - p[n * 3 + 0];
        const float r1 = p[nb * 3 + 1] - p[n * 3 + 1];
        const float r2 = p[nb * 3 + 2] - p[n * 3 + 2];
        const float t0 = c0 + r0 * w00 + r1 * w10 + r2 * w20;
        const float t1 = c1 + r0 * w01 + r1 * w11 + r2 * w21;
        const float t2 = c2 + r0 * w02 + r1 * w12 + r2 * w22;
        s0 += t0; s1 += t1; s2 += t2;
        q0 += t0 * t0; q1 += t1 * t1; q2 += t2 * t2;
    }
    atomicAdd(&sred[0], s0); atomicAdd(&sred[1], s1); atomicAdd(&sred[2], s2);
    atomicAdd(&sred[3], q0); atomicAdd(&sred[4], q1); atomicAdd(&sred[5], q2);
    __syncthreads();
    if (tid < 6) atomicAdd(&ws[ST_OFF + tid], sred[tid]);
}

// ---------------------------------------------------------------------------
// K1: xq/xk/xv projections via MFMA + T' (bn1+relu applied at creation).
// grid=512 x 256: wave = 2 groups of 16 points. No stats, no atomics.
// ---------------------------------------------------------------------------
__global__ __launch_bounds__(256) void k1_proj(
    const float* __restrict__ p, const float* __restrict__ x, const int* __restrict__ idx,
    const float* __restrict__ bq, const float* __restrict__ bk, const float* __restrict__ bv,
    const float* __restrict__ Wp1, const float* __restrict__ bp1,
    const float* __restrict__ gp, const float* __restrict__ bp_bn,
    float* __restrict__ ws)
{
    u16* wsu = (u16*)ws;
    const int tid   = threadIdx.x;
    const int lane  = tid & 63;
    const int wid   = tid >> 6;
    const int col16 = lane & 15;
    const int quad  = lane >> 4;

    // A1/B1 from global BN1 sums
    const float invM = 1.0f / (float)MTOT;
    float A1[3], B1[3];
#pragma unroll
    for (int a = 0; a < 3; ++a) {
        const float mean = ws[ST_OFF + a] * invM;
        const float var  = ws[ST_OFF + 3 + a] * invM - mean * mean;
        const float sc = gp[a] * rsqrtf(var + EPSb);
        A1[a] = sc; B1[a] = bp_bn[a] - mean * sc;
    }

    bf16x8 bf[3][4][2];
#pragma unroll
    for (int M = 0; M < 3; ++M)
#pragma unroll
        for (int t = 0; t < 4; ++t)
#pragma unroll
            for (int h = 0; h < 2; ++h)
                bf[M][t][h] = *(const bf16x8*)&wsu[WTQ_US +
                    (unsigned)(M * 4096 + (t * 16 + col16) * 64 + h * 32 + quad * 8)];

    float bq_t[4], bk_t[4], bv_t[4];
#pragma unroll
    for (int t = 0; t < 4; ++t) {
        bq_t[t] = bq[t * 16 + col16];
        bk_t[t] = bk[t * 16 + col16];
        bv_t[t] = bv[t * 16 + col16];
    }

    float* xq   = ws + XQ_OFF;
    u16*  xkb   = wsu + XK_US;
    u16*  xvb   = wsu + XV_US;

    const int gw = blockIdx.x * 4 + wid;              // 0..2047
#pragma unroll
    for (int g = 0; g < 2; ++g) {
        const int n0 = (gw * 2 + g) * 16;
        const float* xrow = x + (unsigned)(n0 + col16) * 64u;
        const float4 fa0 = *(const float4*)&xrow[quad * 8];
        const float4 fa1 = *(const float4*)&xrow[quad * 8 + 4];
        const float4 fb0 = *(const float4*)&xrow[32 + quad * 8];
        const float4 fb1 = *(const float4*)&xrow[32 + quad * 8 + 4];
        const bf16x8 a0 = pack_bf8(fa0, fa1);
        const bf16x8 a1 = pack_bf8(fb0, fb1);

#pragma unroll
        for (int t = 0; t < 4; ++t) {
            f32x4 aq = {0,0,0,0}, ak = {0,0,0,0}, av = {0,0,0,0};
            aq = __builtin_amdgcn_mfma_f32_16x16x32_bf16(a0, bf[0][t][0], aq, 0, 0, 0);
            aq = __builtin_amdgcn_mfma_f32_16x16x32_bf16(a1, bf[0][t][1], aq, 0, 0, 0);
            ak = __builtin_amdgcn_mfma_f32_16x16x32_bf16(a0, bf[1][t][0], ak, 0, 0, 0);
            ak = __builtin_amdgcn_mfma_f32_16x16x32_bf16(a1, bf[1][t][1], ak, 0, 0, 0);
            av = __builtin_amdgcn_mfma_f32_16x16x32_bf16(a0, bf[2][t][0], av, 0, 0, 0);
            av = __builtin_amdgcn_mfma_f32_16x16x32_bf16(a1, bf[2][t][1], av, 0, 0, 0);
#pragma unroll
            for (int r = 0; r < 4; ++r) {
                const unsigned row = (unsigned)(n0 + quad * 4 + r);
                const unsigned o   = row * 64u + (unsigned)(t * 16 + col16);
                xq[o]  = aq[r] + bq_t[t];
                xkb[o] = f2bf(ak[r] + bk_t[t]);
                xvb[o] = f2bf(av[r] + bv_t[t]);
            }
        }
    }

    // ---- T' = relu(bn1(t)) for this block's 2048 pairs ----
    const int base = blockIdx.x * 128;
    const float w00 = Wp1[0], w01 = Wp1[1], w02 = Wp1[2];
    const float w10 = Wp1[3], w11 = Wp1[4], w12 = Wp1[5];
    const float w20 = Wp1[6], w21 = Wp1[7], w22 = Wp1[8];
    const float c0 = bp1[0], c1 = bp1[1], c2 = bp1[2];
#pragma unroll
    for (int m = 0; m < 8; ++m) {
        const int pl = tid + m * 256;            // 0..2047
        const int n  = base + (pl >> 4);
        const unsigned gpair = (unsigned)(base * 16 + pl);
        const int nb = idx[gpair];
        const float r0 = p[nb * 3 + 0] - p[n * 3 + 0];
        const float r1 = p[nb * 3 + 1] - p[n * 3 + 1];
        const float r2 = p[nb * 3 + 2] - p[n * 3 + 2];
        const float t0 = c0 + r0 * w00 + r1 * w10 + r2 * w20;
        const float t1 = c1 + r0 * w01 + r1 * w11 + r2 * w21;
        const float t2 = c2 + r0 * w02 + r1 * w12 + r2 * w22;
        ws[T_OFF + gpair * 3u + 0u] = fmaxf(fmaf(t0, A1[0], B1[0]), 0.0f);
        ws[T_OFF + gpair * 3u + 1u] = fmaxf(fmaf(t1, A1[1], B1[1]), 0.0f);
        ws[T_OFF + gpair * 3u + 2u] = fmaxf(fmaf(t2, A1[2], B1[2]), 0.0f);
    }
}

// ---------------------------------------------------------------------------
// K2: SAMPLED BN2 stats over w0 = xk[idx] - xq + pr (every 8th point).
// grid=512 x 256, wave = 4 sampled points. NO stores.
// ---------------------------------------------------------------------------
__global__ __launch_bounds__(256) void k2_bn2(
    const int* __restrict__ idx,
    const float* __restrict__ Wp2, const float* __restrict__ bp2,
    float* __restrict__ ws)
{
    u16* wsu = (u16*)ws;
    __shared__ float ss[64], sq[64];
    const int tid = threadIdx.x;
    const int lane = tid & 63;
    const int gw = blockIdx.x * 4 + (tid >> 6);       // 0..2047
    if (tid < 64) { ss[tid] = 0.0f; sq[tid] = 0.0f; }

    const float wp20 = Wp2[lane], wp21 = Wp2[64 + lane], wp22 = Wp2[128 + lane];
    const float bp2c = bp2[lane];
    const float* xq  = ws + XQ_OFF;
    const float* T   = ws + T_OFF;
    const u16*  xkb  = wsu + XK_US;

    float s = 0.0f, q = 0.0f;

    for (int nn = 0; nn < 4; ++nn) {
        const int nu = __builtin_amdgcn_readfirstlane((gw * 4 + nn) * 8);

        const int4* ir4 = (const int4*)(idx + (unsigned)nu * 16u);
        const int4 i0 = ir4[0], i1 = ir4[1], i2 = ir4[2], i3 = ir4[3];
        const int nbs[16] = { i0.x, i0.y, i0.z, i0.w, i1.x, i1.y, i1.z, i1.w,
                              i2.x, i2.y, i2.z, i2.w, i3.x, i3.y, i3.z, i3.w };
        u16 kr[16];
#pragma unroll
        for (int j = 0; j < 16; ++j) kr[j] = xkb[(unsigned)nbs[j] * 64u + lane];

        float tr[48];
        const float4* Tr4 = (const float4*)(T + (unsigned)nu * 48u);
#pragma unroll
        for (int c = 0; c < 12; ++c) {
            const float4 v = Tr4[c];
            tr[4 * c + 0] = v.x; tr[4 * c + 1] = v.y;
            tr[4 * c + 2] = v.z; tr[4 * c + 3] = v.w;
        }
        const float xqc  = xq[(unsigned)nu * 64u + lane];
        const float base = bp2c - xqc;

#pragma unroll
        for (int j = 0; j < 16; ++j) {
            const float prx = base + tr[3 * j + 0] * wp20
                                   + tr[3 * j + 1] * wp21
                                   + tr[3 * j + 2] * wp22;
            const float w0 = bf2f(kr[j]) + prx;
            s += w0; q = fmaf(w0, w0, q);
        }
    }
    __syncthreads();
    atomicAdd(&ss[lane], s); atomicAdd(&sq[lane], q);
    __syncthreads();
    if (tid < 64) {
        atomicAdd(&ws[ST_OFF + 6 + tid], ss[tid]);
        atomicAdd(&ws[ST_OFF + 70 + tid], sq[tid]);
    }
}

// ---------------------------------------------------------------------------
// K2b: SAMPLED BN3 stats — w1 = relu(bn2(w0)) @ Ww1 + bw1 for every 8th
// point (same MFMA path as k34). grid=256 x 256.
// ---------------------------------------------------------------------------
__global__ __launch_bounds__(256) void k2b_bn3(
    const int* __restrict__ idx,
    const float* __restrict__ Wp2, const float* __restrict__ bp2,
    const float* __restrict__ gw1, const float* __restrict__ bw1_bn,
    const float* __restrict__ bw1,
    float* __restrict__ ws)
{
    u16* wsu = (u16*)ws;
    __shared__ float s3r[8], q3r[8];
    const int tid   = threadIdx.x;
    const int lane  = tid & 63;
    const int wid   = tid >> 6;
    const int col16 = lane & 15;
    const int quad  = lane >> 4;
    if (tid < 8) { s3r[tid] = 0.0f; q3r[tid] = 0.0f; }
    __syncthreads();

    BN2C cA, cB;
    bn2c_build(cA, quad * 8,      ws, gw1, bw1_bn, bp2, Wp2);
    bn2c_build(cB, 32 + quad * 8, ws, gw1, bw1_bn, bp2, Wp2);

    bf16x8 b0 = {0,0,0,0,0,0,0,0}, b1 = {0,0,0,0,0,0,0,0};
    if (col16 < 8) {
        b0 = *(const bf16x8*)&wsu[WT1_US + (unsigned)(col16 * 64 + quad * 8)];
        b1 = *(const bf16x8*)&wsu[WT1_US + (unsigned)(col16 * 64 + 32 + quad * 8)];
    }
    const float bw1c = (col16 < 8) ? bw1[col16] : 0.0f;

    const float* xq  = ws + XQ_OFF;
    const float* T   = ws + T_OFF;
    const u16*  xkb  = wsu + XK_US;
    const int sg = (blockIdx.x * 4 + wid) * 8;        // sampled-point group base
    float bs = 0.0f, bq2 = 0.0f;

    for (int it = 0; it < 8; ++it) {
        const int nu = __builtin_amdgcn_readfirstlane((sg + it) * 8);

        const int nbv = idx[(unsigned)nu * 16u + (unsigned)col16];
        const u16* grow = xkb + (unsigned)nbv * 64u;
        const uint4 gA = *(const uint4*)(grow + quad * 8);
        const uint4 gB = *(const uint4*)(grow + 32 + quad * 8);

        const float* Trow = T + (unsigned)nu * 48u + (unsigned)col16 * 3u;
        const f32x2 t0v = f32x2{Trow[0], Trow[0]};
        const f32x2 t1v = f32x2{Trow[1], Trow[1]};
        const f32x2 t2v = f32x2{Trow[2], Trow[2]};

        const float* xr = xq + (unsigned)nu * 64u;
        const float4 x0 = *(const float4*)(xr + quad * 8);
        const float4 x1 = *(const float4*)(xr + quad * 8 + 4);
        const float4 x2 = *(const float4*)(xr + 32 + quad * 8);
        const float4 x3 = *(const float4*)(xr + 32 + quad * 8 + 4);

        const bf16x8 a0 = build_frag(cA, t0v, t1v, t2v, gA, x0, x1);
        const bf16x8 a1 = build_frag(cB, t0v, t1v, t2v, gB, x2, x3);

        f32x4 acc = {0.0f, 0.0f, 0.0f, 0.0f};
        acc = __builtin_amdgcn_mfma_f32_16x16x32_bf16(a0, b0, acc, 0, 0, 0);
        acc = __builtin_amdgcn_mfma_f32_16x16x32_bf16(a1, b1, acc, 0, 0, 0);
        if (col16 < 8) {
#pragma unroll
            for (int r = 0; r < 4; ++r) {
                const float o = acc[r] + bw1c;
                bs += o;
                bq2 = fmaf(o, o, bq2);
            }
        }
    }
    if (col16 < 8) {
        atomicAdd(&s3r[col16], bs);
        atomicAdd(&q3r[col16], bq2);
    }
    __syncthreads();
    if (tid < 8) {
        atomicAdd(&ws[ST_OFF + 134 + tid], s3r[tid]);
        atomicAdd(&ws[ST_OFF + 142 + tid], q3r[tid]);
    }
}

// ---------------------------------------------------------------------------
// K34: fused K3+K4. grid=1024 x 256, wave = 16 points, no barriers.
// ---------------------------------------------------------------------------
__global__ __launch_bounds__(256) void k34_fused(
    const int* __restrict__ idx,
    const float* __restrict__ Wp2, const float* __restrict__ bp2,
    const float* __restrict__ gw1, const float* __restrict__ bw1_bn,
    const float* __restrict__ bw1,
    const float* __restrict__ gw2, const float* __restrict__ bw2_bn,
    const float* __restrict__ Ww2, const float* __restrict__ bw2,
    const float* __restrict__ ws, float* __restrict__ out)
{
    const u16* wsu = (const u16*)ws;
    __shared__ float sv3[4][16][8];
    __shared__ float se[4][16][8];
    const int tid   = threadIdx.x;
    const int lane  = tid & 63;
    const int wid   = tid >> 6;
    const int col16 = lane & 15;
    const int quad  = lane >> 4;
    const int tt    = lane & 7;
    const int j1    = lane >> 3;

    const float invM2 = 1.0f / (float)M2TOT;
    BN2C cA, cB;
    bn2c_build(cA, quad * 8,      ws, gw1, bw1_bn, bp2, Wp2);
    bn2c_build(cB, 32 + quad * 8, ws, gw1, bw1_bn, bp2, Wp2);

    bf16x8 b0 = {0,0,0,0,0,0,0,0}, b1 = {0,0,0,0,0,0,0,0};
    if (col16 < 8) {
        b0 = *(const bf16x8*)&wsu[WT1_US + (unsigned)(col16 * 64 + quad * 8)];
        b1 = *(const bf16x8*)&wsu[WT1_US + (unsigned)(col16 * 64 + 32 + quad * 8)];
    }
    const float bw1c = (col16 < 8) ? bw1[col16] : 0.0f;
    // bn3 (sampled stats) by output channel col16&7, bw1 bias folded in
    const int   c3    = col16 & 7;
    const float mean3 = ws[ST_OFF + 134 + c3] * invM2;
    const float var3  = ws[ST_OFF + 142 + c3] * invM2 - mean3 * mean3;
    const float A3c   = gw2[c3] * rsqrtf(var3 + EPSb);
    const float B3f   = fmaf(A3c, bw1c, bw2_bn[c3] - mean3 * A3c);
    // Ww2 by tt (softmax-logit matmul) + aggregation constants
    float ww2c[8];
#pragma unroll
    for (int u = 0; u < 8; ++u) ww2c[u] = Ww2[u * 8 + tt];
    const float bw2c = bw2[tt];
    const float wp20 = Wp2[lane], wp21 = Wp2[64 + lane], wp22 = Wp2[128 + lane];
    const float bp2c = bp2[lane];

    const float* xq  = ws + XQ_OFF;
    const float* T   = ws + T_OFF;
    const u16*  xkb  = wsu + XK_US;
    const u16*  xvb  = wsu + XV_US;

    const int n0 = (blockIdx.x * 4 + wid) * 16;
    for (int it = 0; it < 16; ++it) {
        const int nu = __builtin_amdgcn_readfirstlane(n0 + it);

        // scalar idx row (for xv gather)
        const int4* ir4 = (const int4*)(idx + (unsigned)nu * 16u);
        const int4 i0 = ir4[0], i1 = ir4[1], i2 = ir4[2], i3 = ir4[3];
        const int nbs[16] = { i0.x, i0.y, i0.z, i0.w, i1.x, i1.y, i1.z, i1.w,
                              i2.x, i2.y, i2.z, i2.w, i3.x, i3.y, i3.z, i3.w };
        // per-lane pair row (MFMA A gather)
        const int nbv = idx[(unsigned)nu * 16u + (unsigned)col16];
        const u16* grow = xkb + (unsigned)nbv * 64u;
        const uint4 gA = *(const uint4*)(grow + quad * 8);
        const uint4 gB = *(const uint4*)(grow + 32 + quad * 8);
        // xv gather (lane = channel) — issue early to overlap MFMA chain
        u16 xvr[16];
#pragma unroll
        for (int j = 0; j < 16; ++j) xvr[j] = xvb[(unsigned)nbs[j] * 64u + lane];

        // per-lane t' (MFMA path) — T already bn1+relu'd
        const float* Trow = T + (unsigned)nu * 48u + (unsigned)col16 * 3u;
        const f32x2 t0v = f32x2{Trow[0], Trow[0]};
        const f32x2 t1v = f32x2{Trow[1], Trow[1]};
        const f32x2 t2v = f32x2{Trow[2], Trow[2]};
        // scalar t' row (aggregation path)
        float tr[48];
        const float4* Tr4 = (const float4*)(T + (unsigned)nu * 48u);
#pragma unroll
        for (int c = 0; c < 12; ++c) {
            const float4 v = Tr4[c];
            tr[4 * c + 0] = v.x; tr[4 * c + 1] = v.y;
            tr[4 * c + 2] = v.z; tr[4 * c + 3] = v.w;
        }
        // xq row (wave-uniform, quad-dependent chunks)
        const float* xr = xq + (unsigned)nu * 64u;
        const float4 x0 = *(const float4*)(xr + quad * 8);
        const float4 x1 = *(const float4*)(xr + quad * 8 + 4);
        const float4 x2 = *(const float4*)(xr + 32 + quad * 8);
        const float4 x3 = *(const float4*)(xr + 32 + quad * 8 + 4);

        // build A fragments (packed math + cvt_pk)
        const bf16x8 a0 = build_frag(cA, t0v, t1v, t2v, gA, x0, x1);
        const bf16x8 a1 = build_frag(cB, t0v, t1v, t2v, gB, x2, x3);

        f32x4 acc = {0.0f, 0.0f, 0.0f, 0.0f};
        acc = __builtin_amdgcn_mfma_f32_16x16x32_bf16(a0, b0, acc, 0, 0, 0);
        acc = __builtin_amdgcn_mfma_f32_16x16x32_bf16(a1, b1, acc, 0, 0, 0);

        // bn3 + relu epilogue -> wave-private LDS (C layout: row=quad*4+r)
        if (col16 < 8) {
#pragma unroll
            for (int r = 0; r < 4; ++r)
                sv3[wid][quad * 4 + r][col16] = fmaxf(fmaf(A3c, acc[r], B3f), 0.0f);
        }
        // 8x8 matmul: logits for neighbors j1 and j1+8 at plane tt
        float s0 = bw2c, s1 = bw2c;
#pragma unroll
        for (int u = 0; u < 8; ++u) {
            s0 = fmaf(sv3[wid][j1][u], ww2c[u], s0);
            s1 = fmaf(sv3[wid][j1 + 8][u], ww2c[u], s1);
        }
        // softmax over 16 neighbors: butterfly across the 8 lanes sharing tt
        float mx = fmaxf(s0, s1);
        mx = fmaxf(mx, __shfl_xor(mx, 8));
        mx = fmaxf(mx, __shfl_xor(mx, 16));
        mx = fmaxf(mx, __shfl_xor(mx, 32));
        const float e0 = __expf(s0 - mx);
        const float e1 = __expf(s1 - mx);
        float sm = e0 + e1;
        sm += __shfl_xor(sm, 8);
        sm += __shfl_xor(sm, 16);
        sm += __shfl_xor(sm, 32);
        const float rs = __builtin_amdgcn_rcpf(sm);
        se[wid][j1][tt]     = e0 * rs;
        se[wid][j1 + 8][tt] = e1 * rs;

        // factored aggregation: out = sum(e*xv) + (sum(e*t')).Wp2col + bp2c
        float xvacc = 0.0f, ta0 = 0.0f, ta1 = 0.0f, ta2 = 0.0f;
#pragma unroll
        for (int j = 0; j < 16; ++j) {
            const float ej = se[wid][j][tt];
            xvacc = fmaf(bf2f(xvr[j]), ej, xvacc);
            ta0 = fmaf(tr[3 * j + 0], ej, ta0);
            ta1 = fmaf(tr[3 * j + 1], ej, ta1);
            ta2 = fmaf(tr[3 * j + 2], ej, ta2);
        }
        out[(unsigned)nu * 64u + lane] =
            fmaf(ta0, wp20, fmaf(ta1, wp21, fmaf(ta2, wp22, xvacc + bp2c)));
    }
}

extern "C" void kernel_launch(void* const* d_in, const int* in_sizes, int n_in,
                              void* d_out, int out_size, void* d_ws, size_t ws_size,
                              hipStream_t stream)
{
    const float* p      = (const float*)d_in[0];
    const float* x      = (const float*)d_in[1];
    const int*   idx    = (const int*)d_in[2];
    const float* Wq     = (const float*)d_in[3];
    const float* bq     = (const float*)d_in[4];
    const float* Wk     = (const float*)d_in[5];
    const float* bk     = (const float*)d_in[6];
    const float* Wv     = (const float*)d_in[7];
    const float* bv     = (const float*)d_in[8];
    const float* Wp1    = (const float*)d_in[9];
    const float* bp1    = (const float*)d_in[10];
    const float* gp     = (const float*)d_in[11];
    const float* bp_bn  = (const float*)d_in[12];
    const float* Wp2    = (const float*)d_in[13];
    const float* bp2    = (const float*)d_in[14];
    const float* gw1    = (const float*)d_in[15];
    const float* bw1_bn = (const float*)d_in[16];
    const float* Ww1    = (const float*)d_in[17];
    const float* bw1    = (const float*)d_in[18];
    const float* gw2    = (const float*)d_in[19];
    const float* bw2_bn = (const float*)d_in[20];
    const float* Ww2    = (const float*)d_in[21];
    const float* bw2    = (const float*)d_in[22];
    float* ws  = (float*)d_ws;
    float* out = (float*)d_out;
    (void)in_sizes; (void)n_in; (void)out_size; (void)ws_size;

    hipMemsetAsync((char*)d_ws + (size_t)ST_OFF * 4, 0, 150 * sizeof(float), stream);

    k0_mom_tab<<<512, 256, 0, stream>>>(p, idx, Wq, Wk, Wv, Ww1, Wp1, bp1, ws);
    k1_proj<<<512, 256, 0, stream>>>(p, x, idx, bq, bk, bv, Wp1, bp1, gp, bp_bn, ws);
    k2_bn2<<<512, 256, 0, stream>>>(idx, Wp2, bp2, ws);
    k2b_bn3<<<256, 256, 0, stream>>>(idx, Wp2, bp2, gw1, bw1_bn, bw1, ws);
    k34_fused<<<1024, 256, 0, stream>>>(idx, Wp2, bp2, gw1, bw1_bn, bw1,
                                        gw2, bw2_bn, Ww2, bw2, ws, out);
}